// Round 6
// baseline (166.473 us; speedup 1.0000x reference)
//
#include <hip/hip_runtime.h>
#include <hip/hip_bf16.h>

#define HH 1024
#define LL 512
#define NT 16              // 512/32 row-tiles
#define NTRI 136           // NT*(NT+1)/2 triangular tiles

typedef __attribute__((ext_vector_type(8))) short bf16x8;
typedef __attribute__((ext_vector_type(4))) float f32x4;
typedef __attribute__((ext_vector_type(2))) float f32x2;

static constexpr float C_EXP = 2.8853900817779268f; // 2*log2(e)

// pack 8 fp32 -> 8 bf16 (RNE) as uint4
static __device__ __forceinline__ uint4 pack8(float4 a, float4 b) {
    union { uint4 u; __hip_bfloat162 h[4]; } r;
    r.h[0] = __float22bfloat162_rn(make_float2(a.x, a.y));
    r.h[1] = __float22bfloat162_rn(make_float2(a.z, a.w));
    r.h[2] = __float22bfloat162_rn(make_float2(b.x, b.y));
    r.h[3] = __float22bfloat162_rn(make_float2(b.z, b.w));
    return r.u;
}

// ---------------------------------------------------------------------------
// Kernel 1: bf16 MFMA projection, 64m x 32n tiles, grid 512 (unchanged).
//   n < 1024:  Ea[m][n] = exp2(C*(acc+b1[n]));  else Eb[m][n-1024] = exp2(C*acc)
// ---------------------------------------------------------------------------
__global__ __launch_bounds__(256, 4) void proj_mfma_kernel(
    const float* __restrict__ lm, const float* __restrict__ W1,
    const float* __restrict__ b1, float* __restrict__ Ea, float* __restrict__ Eb)
{
    __shared__ ushort As[64][136];  // 136 us = 68 dw = 4 mod 32 banks: <=2-way, free
    __shared__ ushort Bs[32][136];

    const int tid  = threadIdx.x;
    const int lane = tid & 63;
    const int w    = tid >> 6;
    const int b    = blockIdx.x;          // 0..511
    const int xcd  = b & 7;
    const int idx  = b >> 3;              // 0..63
    const int nbase = (xcd * 8 + (idx & 7)) * 32;   // 0..2047 (32-wide n-tile)
    const int mbase = (idx >> 3) * 64;              // 0..448
    const int wm   = w * 16;
    const int sel  = nbase >> 10;         // block-uniform: Wa(0)/Wb(1)
    const int nrow = nbase & 1023;

    const int frow = lane & 15;
    const int q8   = (lane >> 4) * 8;

    f32x4 acc[2] = {};

    for (int kb = 0; kb < HH; kb += 128) {
        __syncthreads();
        {   // stage A (64x128 -> 1024 chunks) + B (32x128 -> 512 chunks), 6/thread
            int p = tid;
#pragma unroll
            for (int it = 0; it < 4; ++it, p += 256) {      // A chunks
                const int row = p >> 4, c8 = (p & 15) * 8;
                const float* pa = &lm[(mbase + row) * HH + kb + c8];
                *(uint4*)&As[row][c8] = pack8(*(const float4*)pa, *(const float4*)(pa + 4));
            }
            int q = tid;
#pragma unroll
            for (int it = 0; it < 2; ++it, q += 256) {      // B chunks
                const int row = q >> 4, c8 = (q & 15) * 8;
                const float* pw = &W1[(nrow + row) * 2048 + sel * 1024 + kb + c8];
                *(uint4*)&Bs[row][c8] = pack8(*(const float4*)pw, *(const float4*)(pw + 4));
            }
        }
        __syncthreads();

#pragma unroll
        for (int s = 0; s < 4; ++s) {
            const bf16x8 a = *(const bf16x8*)&As[wm + frow][s * 32 + q8];
#pragma unroll
            for (int nf = 0; nf < 2; ++nf) {
                const bf16x8 bb = *(const bf16x8*)&Bs[nf * 16 + frow][s * 32 + q8];
                acc[nf] = __builtin_amdgcn_mfma_f32_16x16x32_bf16(a, bb, acc[nf], 0, 0, 0);
            }
        }
    }

    // D mapping: col=lane&15 (n), row=(lane>>4)*4+reg (m)
    const int col = lane & 15;
    const int rq  = (lane >> 4) * 4;
    const int m0  = mbase + wm + rq;
    const bool isA = sel == 0;            // block-uniform
#pragma unroll
    for (int nf = 0; nf < 2; ++nf) {
        const int nn = (nrow + nf * 16 + col);
        if (isA) {
            const float bb = b1[nn];
#pragma unroll
            for (int r = 0; r < 4; ++r)
                Ea[(m0 + r) * HH + nn] = __builtin_amdgcn_exp2f(C_EXP * (acc[nf][r] + bb));
        } else {
#pragma unroll
            for (int r = 0; r < 4; ++r)
                Eb[(m0 + r) * HH + nn] = __builtin_amdgcn_exp2f(C_EXP * acc[nf][r]);
        }
    }
}

// ---------------------------------------------------------------------------
// Kernel 2: triangular pairwise contraction. STRUCTURAL CHANGE vs r5:
// LDS holds ONLY the j-side tiles (per-lane row-indexed reads need LDS);
// i-side tiles are BROADCAST reads (address independent of tx) served
// straight from global/L2 via base-pointer + offset-immediate (zero per-iter
// address VALU); W2 reads are wave-uniform -> scalar loads. LDS 32->16 KB
// and __launch_bounds__(256,6) -> up to 6 blocks/CU resident (vs measured
// 2.4) to hide the stage/load latency that capped r5 at 70% VALUBusy.
// Inner math unchanged (measured-equal scalar floor ~4.75 ops/sigmoid).
// ---------------------------------------------------------------------------
__global__ __launch_bounds__(256, 6) void pair_kernel(
    const float* __restrict__ Ea, const float* __restrict__ Eb,
    const float* __restrict__ W2, float* __restrict__ pbuf, int slice)
{
    __shared__ float tl[2][32][64];   // 16384 B: [0]=Ea[j] (xor), [1]=Eb[j] (xor)

    const int tid = threadIdx.x;
    const int tx  = tid & 15;
    const int ty  = tid >> 4;         // 0..15

    int tt = blockIdx.x, bi = 0, rem = NT;          // triangular decode
    while (tt >= rem) { tt -= rem; --rem; ++bi; }
    const int bj    = bi + tt;
    const int ibase = bi * 32;
    const int jbase = bj * 32;
    const int k0    = blockIdx.y * slice;

    // named scalar accumulators: acc<ii><jj>_<channel>
    float a00_0 = 0.f, a00_1 = 0.f, a01_0 = 0.f, a01_1 = 0.f;
    float a10_0 = 0.f, a10_1 = 0.f, a11_0 = 0.f, a11_1 = 0.f;

    for (int kb = 0; kb < slice; kb += 64) {
        if (kb) __syncthreads();
        {   // stage 2 j-tiles x 32 rows x 64 floats = 1024 float4, 4/thread
            int p = tid;
#pragma unroll
            for (int it = 0; it < 4; ++it, p += 256) {
                const int tile = p >> 9;             // compile-time per it
                const int row  = (p >> 4) & 31;
                const int c4   = p & 15;
                const float* src = tile ? Eb : Ea;
                const float4 v = *(const float4*)&src[(jbase + row) * HH + k0 + kb + c4 * 4];
                const int c4s = c4 ^ (row & 15);     // xor float4-column swizzle
                *(float4*)&tl[tile][row][c4s * 4] = v;
            }
        }
        __syncthreads();

        // i-side base pointers: uniform across tx (16-lane broadcast, L2-hot);
        // per-h4 access via offset immediates (h4*16B <= 240 fits 13-bit simm)
        const float* pAi0 = &Ea[(ibase + ty) * HH + k0 + kb];
        const float* pAi1 = &Ea[(ibase + ty + 16) * HH + k0 + kb];
        const float* pBi0 = &Eb[(ibase + ty) * HH + k0 + kb];
        const float* pBi1 = &Eb[(ibase + ty + 16) * HH + k0 + kb];
        const float* pW0  = &W2[k0 + kb];            // fully uniform -> s_load
        const float* pW1  = &W2[HH + k0 + kb];

#pragma unroll 2
        for (int h4 = 0; h4 < 16; ++h4) {
            const int sx = (h4 ^ tx) * 4;            // xor-swizzled column
            const float4 Aj0 = *(const float4*)&tl[0][tx][sx];
            const float4 Aj1 = *(const float4*)&tl[0][tx + 16][sx];
            const float4 Bj0 = *(const float4*)&tl[1][tx][sx];
            const float4 Bj1 = *(const float4*)&tl[1][tx + 16][sx];
            const float4 Ai0 = *(const float4*)&pAi0[h4 * 4];
            const float4 Ai1 = *(const float4*)&pAi1[h4 * 4];
            const float4 Bi0 = *(const float4*)&pBi0[h4 * 4];
            const float4 Bi1 = *(const float4*)&pBi1[h4 * 4];
            const float4 w0q = *(const float4*)&pW0[h4 * 4];
            const float4 w1q = *(const float4*)&pW1[h4 * 4];

            // d = 1 + Eb_i*Ea_j ; e = 1 + Ea_i*Eb_j ; u = 1/d + 1/e = n/(d*e)
            // batch-rcp 4 m's: R = rcp(m0m1m2m3); 1/(m0m1)=R*t23; q_k = n_k*m_part*Rx
#define PAIR(AIv, BIv, AJv, BJv, A0, A1)                                        \
            {                                                                    \
                const float d0 = fmaf(BIv.x, AJv.x, 1.f);                        \
                const float d1 = fmaf(BIv.y, AJv.y, 1.f);                        \
                const float d2 = fmaf(BIv.z, AJv.z, 1.f);                        \
                const float d3 = fmaf(BIv.w, AJv.w, 1.f);                        \
                const float e0 = fmaf(AIv.x, BJv.x, 1.f);                        \
                const float e1 = fmaf(AIv.y, BJv.y, 1.f);                        \
                const float e2 = fmaf(AIv.z, BJv.z, 1.f);                        \
                const float e3 = fmaf(AIv.w, BJv.w, 1.f);                        \
                const float m0 = d0 * e0, m1 = d1 * e1;                          \
                const float m2 = d2 * e2, m3 = d3 * e3;                          \
                const float n0 = d0 + e0, n1 = d1 + e1;                          \
                const float n2 = d2 + e2, n3 = d3 + e3;                          \
                const float t01 = m0 * m1, t23 = m2 * m3;                        \
                const float R  = __builtin_amdgcn_rcpf(t01 * t23);               \
                const float Ra = R * t23, Rb = R * t01;                          \
                const float q0 = n0 * m1 * Ra, q1 = n1 * m0 * Ra;                \
                const float q2 = n2 * m3 * Rb, q3 = n3 * m2 * Rb;                \
                A0 = fmaf(q0, w0q.x, fmaf(q1, w0q.y,                             \
                     fmaf(q2, w0q.z, fmaf(q3, w0q.w, A0))));                     \
                A1 = fmaf(q0, w1q.x, fmaf(q1, w1q.y,                             \
                     fmaf(q2, w1q.z, fmaf(q3, w1q.w, A1))));                     \
            }
            PAIR(Ai0, Bi0, Aj0, Bj0, a00_0, a00_1)
            PAIR(Ai0, Bi0, Aj1, Bj1, a01_0, a01_1)
            PAIR(Ai1, Bi1, Aj0, Bj0, a10_0, a10_1)
            PAIR(Ai1, Bi1, Aj1, Bj1, a11_0, a11_1)
#undef PAIR
        }
    }

    float* pb = pbuf + ((size_t)blockIdx.y * NTRI + blockIdx.x) * 2048;
    {
        const int li0 = ty, li1 = ty + 16, lj0 = tx, lj1 = tx + 16;
        *(f32x2*)&pb[(li0 * 32 + lj0) * 2] = (f32x2){a00_0, a00_1};
        *(f32x2*)&pb[(li0 * 32 + lj1) * 2] = (f32x2){a01_0, a01_1};
        *(f32x2*)&pb[(li1 * 32 + lj0) * 2] = (f32x2){a10_0, a10_1};
        *(f32x2*)&pb[(li1 * 32 + lj1) * 2] = (f32x2){a11_0, a11_1};
    }
}

// ---------------------------------------------------------------------------
// Kernel 3: combine (proven form): out = wsum[c]+b2[c] - sum_z pbuf;
// scatter to (i,j) and (j,i). 1088 blocks, 2-way ILP on z.
// ---------------------------------------------------------------------------
__global__ __launch_bounds__(256) void combine_kernel(
    const float* __restrict__ pbuf, const float* __restrict__ W2,
    const float* __restrict__ b2, float* __restrict__ out, int nz)
{
    __shared__ float s_ws[2];

    const int tid = threadIdx.x;
    if (tid < 128) {
        const int c = tid >> 6, l = tid & 63;
        float s = 0.f;
#pragma unroll
        for (int q = 0; q < 4; ++q) {
            const float4 v = *(const float4*)&W2[c * HH + (l + q * 64) * 4];
            s += v.x + v.y + v.z + v.w;
        }
#pragma unroll
        for (int off = 32; off; off >>= 1) s += __shfl_down(s, off, 64);
        if (l == 0) s_ws[c] = s + b2[c];
    }
    __syncthreads();

    const int idx   = blockIdx.x * 256 + tid;   // 0 .. 136*2048-1
    const int t     = idx >> 11;                // block-uniform
    const int local = idx & 2047;
    int tt = t, bi = 0, rem = NT;
    while (tt >= rem) { tt -= rem; --rem; ++bi; }
    const int bj = bi + tt;

    float s0 = 0.f, s1 = 0.f;
    for (int z = 0; z < nz; z += 2) {   // nz is even
        s0 += pbuf[((size_t)z * NTRI + t) * 2048 + local];
        s1 += pbuf[((size_t)(z + 1) * NTRI + t) * 2048 + local];
    }
    const float s = s0 + s1;

    const int li = local >> 6;
    const int lj = (local >> 1) & 31;
    const int c  = local & 1;
    const float v = s_ws[c] - s;

    const int i = bi * 32 + li;
    const int j = bj * 32 + lj;
    out[(i * LL + j) * 2 + c] = v;
    out[(j * LL + i) * 2 + c] = v;   // diagonal tiles: same-value rewrite, benign
}

extern "C" void kernel_launch(void* const* d_in, const int* in_sizes, int n_in,
                              void* d_out, int out_size, void* d_ws, size_t ws_size,
                              hipStream_t stream)
{
    const float* lm = (const float*)d_in[0];
    const float* W1 = (const float*)d_in[1];
    const float* b1 = (const float*)d_in[2];
    const float* W2 = (const float*)d_in[3];
    const float* b2 = (const float*)d_in[4];
    float* out = (float*)d_out;

    char* ws = (char*)d_ws;
    float* Ea   = (float*)ws;                            // 2 MB
    float* Eb   = (float*)(ws + (2u << 20));             // 2 MB
    float* pbuf = (float*)(ws + (4u << 20) + 64);        // nz * 1.11 MB

    const size_t ubase = (4u << 20) + 64;
    const size_t pb16  = (size_t)16 * NTRI * 2048 * 4;   // 17.8 MB
    const int nz = (ws_size >= ubase + pb16) ? 16 : 8;   // ws_size const/session
    const int slice = HH / nz;

    proj_mfma_kernel<<<512, 256, 0, stream>>>(lm, W1, b1, Ea, Eb);
    pair_kernel<<<dim3(NTRI, nz), 256, 0, stream>>>(Ea, Eb, W2, pbuf, slice);
    combine_kernel<<<(NTRI * 2048) / 256, 256, 0, stream>>>(pbuf, W2, b2, out, nz);
}

// Round 7
// 139.061 us; speedup vs baseline: 1.1971x; 1.1971x over previous
//
#include <hip/hip_runtime.h>
#include <hip/hip_bf16.h>

#define HH 1024
#define LL 512
#define NT 16              // 512/32 row-tiles
#define NTRI 136           // NT*(NT+1)/2 triangular tiles
#define NZ 8               // z-slices (slice = 128 -> 2 K-iters/block)

typedef __attribute__((ext_vector_type(8))) short bf16x8;
typedef __attribute__((ext_vector_type(4))) float f32x4;
typedef __attribute__((ext_vector_type(2))) float f32x2;

static constexpr float C_EXP = 2.8853900817779268f; // 2*log2(e)

// pack 8 fp32 -> 8 bf16 (RNE) as uint4
static __device__ __forceinline__ uint4 pack8(float4 a, float4 b) {
    union { uint4 u; __hip_bfloat162 h[4]; } r;
    r.h[0] = __float22bfloat162_rn(make_float2(a.x, a.y));
    r.h[1] = __float22bfloat162_rn(make_float2(a.z, a.w));
    r.h[2] = __float22bfloat162_rn(make_float2(b.x, b.y));
    r.h[3] = __float22bfloat162_rn(make_float2(b.z, b.w));
    return r.u;
}

// ---------------------------------------------------------------------------
// Kernel 1: bf16 MFMA projection, 64m x 32n tiles, grid 512 (measured-equal
// to the grid-256 64x64 original; kept for 2-blocks/CU latency hiding).
//   n < 1024:  Ea[m][n] = exp2(C*(acc+b1[n]));  else Eb[m][n-1024] = exp2(C*acc)
// ---------------------------------------------------------------------------
__global__ __launch_bounds__(256, 4) void proj_mfma_kernel(
    const float* __restrict__ lm, const float* __restrict__ W1,
    const float* __restrict__ b1, float* __restrict__ Ea, float* __restrict__ Eb)
{
    __shared__ ushort As[64][136];  // 136 us = 68 dw = 4 mod 32 banks: <=2-way, free
    __shared__ ushort Bs[32][136];

    const int tid  = threadIdx.x;
    const int lane = tid & 63;
    const int w    = tid >> 6;
    const int b    = blockIdx.x;          // 0..511
    const int xcd  = b & 7;
    const int idx  = b >> 3;              // 0..63
    const int nbase = (xcd * 8 + (idx & 7)) * 32;   // 0..2047 (32-wide n-tile)
    const int mbase = (idx >> 3) * 64;              // 0..448
    const int wm   = w * 16;
    const int sel  = nbase >> 10;         // block-uniform: Wa(0)/Wb(1)
    const int nrow = nbase & 1023;

    const int frow = lane & 15;
    const int q8   = (lane >> 4) * 8;

    f32x4 acc[2] = {};

    for (int kb = 0; kb < HH; kb += 128) {
        __syncthreads();
        {   // stage A (64x128 -> 1024 chunks) + B (32x128 -> 512 chunks), 6/thread
            int p = tid;
#pragma unroll
            for (int it = 0; it < 4; ++it, p += 256) {      // A chunks
                const int row = p >> 4, c8 = (p & 15) * 8;
                const float* pa = &lm[(mbase + row) * HH + kb + c8];
                *(uint4*)&As[row][c8] = pack8(*(const float4*)pa, *(const float4*)(pa + 4));
            }
            int q = tid;
#pragma unroll
            for (int it = 0; it < 2; ++it, q += 256) {      // B chunks
                const int row = q >> 4, c8 = (q & 15) * 8;
                const float* pw = &W1[(nrow + row) * 2048 + sel * 1024 + kb + c8];
                *(uint4*)&Bs[row][c8] = pack8(*(const float4*)pw, *(const float4*)(pw + 4));
            }
        }
        __syncthreads();

#pragma unroll
        for (int s = 0; s < 4; ++s) {
            const bf16x8 a = *(const bf16x8*)&As[wm + frow][s * 32 + q8];
#pragma unroll
            for (int nf = 0; nf < 2; ++nf) {
                const bf16x8 bb = *(const bf16x8*)&Bs[nf * 16 + frow][s * 32 + q8];
                acc[nf] = __builtin_amdgcn_mfma_f32_16x16x32_bf16(a, bb, acc[nf], 0, 0, 0);
            }
        }
    }

    // D mapping: col=lane&15 (n), row=(lane>>4)*4+reg (m)
    const int col = lane & 15;
    const int rq  = (lane >> 4) * 4;
    const int m0  = mbase + wm + rq;
    const bool isA = sel == 0;            // block-uniform
#pragma unroll
    for (int nf = 0; nf < 2; ++nf) {
        const int nn = (nrow + nf * 16 + col);
        if (isA) {
            const float bb = b1[nn];
#pragma unroll
            for (int r = 0; r < 4; ++r)
                Ea[(m0 + r) * HH + nn] = __builtin_amdgcn_exp2f(C_EXP * (acc[nf][r] + bb));
        } else {
#pragma unroll
            for (int r = 0; r < 4; ++r)
                Eb[(m0 + r) * HH + nn] = __builtin_amdgcn_exp2f(C_EXP * acc[nf][r]);
        }
    }
}

// ---------------------------------------------------------------------------
// Kernel 2: triangular pairwise contraction — EXACT round-0 shell + math
// (measured 48.5 us, the best of 3 inner-math forms), with ONE change:
// slice=128 (2 K-iters/block) and a T14 async-stage split: the 2nd tile's
// 8 global loads are issued into registers BEFORE the first barrier so HBM
// latency hides under COMPUTE(0); ds_writes land after compute. r6 proved
// the i-side must stay in LDS (global broadcast reads -> L2 thrash, 2x).
// ---------------------------------------------------------------------------
__global__ __launch_bounds__(256, 5) void pair_kernel(
    const float* __restrict__ Ea, const float* __restrict__ Eb,
    const float* __restrict__ W2, float* __restrict__ pbuf, int slice)
{
    // [0]=Ea[j] (xor), [1]=Ea[i] (plain), [2]=Eb[i] (plain), [3]=Eb[j] (xor)
    __shared__ float tl[4][32][64];   // 32768 B exactly

    const int tid = threadIdx.x;
    const int tx  = tid & 15;
    const int ty  = tid >> 4;         // 0..15

    int tt = blockIdx.x, bi = 0, rem = NT;          // triangular decode
    while (tt >= rem) { tt -= rem; --rem; ++bi; }
    const int bj    = bi + tt;
    const int ibase = bi * 32;
    const int jbase = bj * 32;
    const int k0    = blockIdx.y * slice;

    f32x2 aC0[2] = {}, aC1[2] = {};   // [ii], packed over jj
    const f32x2 one2 = {1.f, 1.f};

    float4 st[8];                     // staging registers (32 VGPR)

// LOADS: 8 float4/thread at h-offset (hh); tile/row/c4 derived from tid+it*256
#define LOADS(hh)                                                              \
    {                                                                          \
        int p = tid;                                                           \
        _Pragma("unroll")                                                      \
        for (int it = 0; it < 8; ++it, p += 256) {                             \
            const int tile = p >> 9;                                           \
            const int row  = (p >> 4) & 31;                                    \
            const int c4   = p & 15;                                           \
            if      (tile == 0) st[it] = *(const float4*)&Ea[(jbase + row) * HH + (hh) + c4 * 4]; \
            else if (tile == 1) st[it] = *(const float4*)&Ea[(ibase + row) * HH + (hh) + c4 * 4]; \
            else if (tile == 2) st[it] = *(const float4*)&Eb[(ibase + row) * HH + (hh) + c4 * 4]; \
            else                st[it] = *(const float4*)&Eb[(jbase + row) * HH + (hh) + c4 * 4]; \
        }                                                                      \
    }

#define STORES()                                                               \
    {                                                                          \
        int p = tid;                                                           \
        _Pragma("unroll")                                                      \
        for (int it = 0; it < 8; ++it, p += 256) {                             \
            const int tile = p >> 9;                                           \
            const int row  = (p >> 4) & 31;                                    \
            const int c4   = p & 15;                                           \
            const int c4s  = (tile == 0 || tile == 3) ? (c4 ^ (row & 15)) : c4;\
            *(float4*)&tl[tile][row][c4s * 4] = st[it];                        \
        }                                                                      \
    }

#define COMPUTE(kb)                                                            \
    _Pragma("unroll 4")                                                        \
    for (int h4 = 0; h4 < 16; ++h4) {                                          \
        const int sx = (h4 ^ tx) * 4;            /* xor-swizzled column */     \
        const float4 Aj0 = *(const float4*)&tl[0][tx][sx];                     \
        const float4 Aj1 = *(const float4*)&tl[0][tx + 16][sx];                \
        const float4 Bj0 = *(const float4*)&tl[3][tx][sx];                     \
        const float4 Bj1 = *(const float4*)&tl[3][tx + 16][sx];                \
        const float4 Ai0 = *(const float4*)&tl[1][ty][h4 * 4];                 \
        const float4 Ai1 = *(const float4*)&tl[1][ty + 16][h4 * 4];            \
        const float4 Bi0 = *(const float4*)&tl[2][ty][h4 * 4];                 \
        const float4 Bi1 = *(const float4*)&tl[2][ty + 16][h4 * 4];            \
        const float4 w0q = *(const float4*)&W2[k0 + (kb) + h4 * 4];            \
        const float4 w1q = *(const float4*)&W2[HH + k0 + (kb) + h4 * 4];       \
        DO_H(Aj0.x, Aj1.x, Bi0.x, Bi1.x, Ai0.x, Ai1.x, Bj0.x, Bj1.x, w0q.x, w1q.x) \
        DO_H(Aj0.y, Aj1.y, Bi0.y, Bi1.y, Ai0.y, Ai1.y, Bj0.y, Bj1.y, w0q.y, w1q.y) \
        DO_H(Aj0.z, Aj1.z, Bi0.z, Bi1.z, Ai0.z, Ai1.z, Bj0.z, Bj1.z, w0q.z, w1q.z) \
        DO_H(Aj0.w, Aj1.w, Bi0.w, Bi1.w, Ai0.w, Ai1.w, Bj0.w, Bj1.w, w0q.w, w1q.w) \
    }

#define DO_H(AJ0v, AJ1v, BI0v, BI1v, AI0v, AI1v, BJ0v, BJ1v, W0s, W1s)        \
    {                                                                          \
        const f32x2 Aj = {AJ0v, AJ1v};                                         \
        const f32x2 Bj = {BJ0v, BJ1v};                                         \
        const f32x2 d0 = __builtin_elementwise_fma((f32x2){BI0v, BI0v}, Aj, one2); \
        const f32x2 d1 = __builtin_elementwise_fma((f32x2){BI1v, BI1v}, Aj, one2); \
        const f32x2 e0 = __builtin_elementwise_fma((f32x2){AI0v, AI0v}, Bj, one2); \
        const f32x2 e1 = __builtin_elementwise_fma((f32x2){AI1v, AI1v}, Bj, one2); \
        const float dp0 = d0.x * d0.y, dp1 = d1.x * d1.y;                      \
        const float ep0 = e0.x * e0.y, ep1 = e1.x * e1.y;                      \
        const float DR = __builtin_amdgcn_rcpf(dp0 * dp1);                     \
        const float ER = __builtin_amdgcn_rcpf(ep0 * ep1);                     \
        const f32x2 dq = (f32x2){DR, DR} * (f32x2){dp1, dp0};                  \
        const f32x2 eq = (f32x2){ER, ER} * (f32x2){ep1, ep0};                  \
        const f32x2 u0 = (f32x2){dq.x, dq.x} * __builtin_shufflevector(d0, d0, 1, 0) \
                       + (f32x2){eq.x, eq.x} * __builtin_shufflevector(e0, e0, 1, 0); \
        const f32x2 u1 = (f32x2){dq.y, dq.y} * __builtin_shufflevector(d1, d1, 1, 0) \
                       + (f32x2){eq.y, eq.y} * __builtin_shufflevector(e1, e1, 1, 0); \
        aC0[0] = __builtin_elementwise_fma(u0, (f32x2){(W0s), (W0s)}, aC0[0]); \
        aC1[0] = __builtin_elementwise_fma(u0, (f32x2){(W1s), (W1s)}, aC1[0]); \
        aC0[1] = __builtin_elementwise_fma(u1, (f32x2){(W0s), (W0s)}, aC0[1]); \
        aC1[1] = __builtin_elementwise_fma(u1, (f32x2){(W1s), (W1s)}, aC1[1]); \
    }

    // --- software-pipelined 2-iteration K loop (slice = 128) ---
    LOADS(k0);                 // tile 0 loads
    STORES();                  // tile 0 ds_writes
    for (int kb = 0; kb < slice; kb += 64) {
        const bool more = (kb + 64 < slice);
        if (more) LOADS(k0 + kb + 64);   // prefetch next tile: flies under compute
        __syncthreads();                 // current tile visible
        COMPUTE(kb)
        if (more) {
            __syncthreads();             // all waves done reading tl
            STORES();                    // next tile ds_writes
        }
    }

#undef DO_H
#undef COMPUTE
#undef STORES
#undef LOADS

    // u0/u1 are jj-packed: value(ii,jj,c) = (c ? aC1 : aC0)[ii][jj]
    float* pb = pbuf + ((size_t)blockIdx.y * NTRI + blockIdx.x) * 2048;
#pragma unroll
    for (int ii = 0; ii < 2; ++ii)
#pragma unroll
        for (int jj = 0; jj < 2; ++jj) {
            const int li = ty + ii * 16, lj = tx + jj * 16;
            const f32x2 v = { jj ? aC0[ii].y : aC0[ii].x,
                              jj ? aC1[ii].y : aC1[ii].x };
            *(f32x2*)&pb[(li * 32 + lj) * 2] = v;
        }
}

// ---------------------------------------------------------------------------
// Kernel 3: combine: out = wsum[c]+b2[c] - sum_z pbuf; scatter (i,j),(j,i).
// nz=8 -> half the pbuf read traffic of the nz=16 baseline. 1088 blocks.
// ---------------------------------------------------------------------------
__global__ __launch_bounds__(256) void combine_kernel(
    const float* __restrict__ pbuf, const float* __restrict__ W2,
    const float* __restrict__ b2, float* __restrict__ out, int nz)
{
    __shared__ float s_ws[2];

    const int tid = threadIdx.x;
    if (tid < 128) {
        const int c = tid >> 6, l = tid & 63;
        float s = 0.f;
#pragma unroll
        for (int q = 0; q < 4; ++q) {
            const float4 v = *(const float4*)&W2[c * HH + (l + q * 64) * 4];
            s += v.x + v.y + v.z + v.w;
        }
#pragma unroll
        for (int off = 32; off; off >>= 1) s += __shfl_down(s, off, 64);
        if (l == 0) s_ws[c] = s + b2[c];
    }
    __syncthreads();

    const int idx   = blockIdx.x * 256 + tid;   // 0 .. 136*2048-1
    const int t     = idx >> 11;                // block-uniform
    const int local = idx & 2047;
    int tt = t, bi = 0, rem = NT;
    while (tt >= rem) { tt -= rem; --rem; ++bi; }
    const int bj = bi + tt;

    float s0 = 0.f, s1 = 0.f, s2 = 0.f, s3 = 0.f;
    for (int z = 0; z < nz; z += 4) {   // nz = 8 -> 2 iterations, 4-way ILP
        s0 += pbuf[((size_t)z * NTRI + t) * 2048 + local];
        s1 += pbuf[((size_t)(z + 1) * NTRI + t) * 2048 + local];
        s2 += pbuf[((size_t)(z + 2) * NTRI + t) * 2048 + local];
        s3 += pbuf[((size_t)(z + 3) * NTRI + t) * 2048 + local];
    }
    const float s = (s0 + s1) + (s2 + s3);

    const int li = local >> 6;
    const int lj = (local >> 1) & 31;
    const int c  = local & 1;
    const float v = s_ws[c] - s;

    const int i = bi * 32 + li;
    const int j = bj * 32 + lj;
    out[(i * LL + j) * 2 + c] = v;
    out[(j * LL + i) * 2 + c] = v;   // diagonal tiles: same-value rewrite, benign
}

extern "C" void kernel_launch(void* const* d_in, const int* in_sizes, int n_in,
                              void* d_out, int out_size, void* d_ws, size_t ws_size,
                              hipStream_t stream)
{
    const float* lm = (const float*)d_in[0];
    const float* W1 = (const float*)d_in[1];
    const float* b1 = (const float*)d_in[2];
    const float* W2 = (const float*)d_in[3];
    const float* b2 = (const float*)d_in[4];
    float* out = (float*)d_out;

    char* ws = (char*)d_ws;
    float* Ea   = (float*)ws;                            // 2 MB
    float* Eb   = (float*)(ws + (2u << 20));             // 2 MB
    float* pbuf = (float*)(ws + (4u << 20) + 64);        // 8 * 1.11 MB = 8.9 MB

    const int nz = NZ;                 // pbuf 8.9 MB; session ws >= 22 MB proven
    const int slice = HH / nz;         // 128 -> 2 K-iters per pair block

    proj_mfma_kernel<<<512, 256, 0, stream>>>(lm, W1, b1, Ea, Eb);
    pair_kernel<<<dim3(NTRI, nz), 256, 0, stream>>>(Ea, Eb, W2, pbuf, slice);
    combine_kernel<<<(NTRI * 2048) / 256, 256, 0, stream>>>(pbuf, W2, b2, out, nz);
}

// Round 8
// 130.664 us; speedup vs baseline: 1.2741x; 1.0643x over previous
//
#include <hip/hip_runtime.h>
#include <hip/hip_bf16.h>

#define HH 1024
#define LL 512
#define TNT 8              // 512/64 row-tiles
#define NTILE 36           // TNT*(TNT+1)/2 triangular 64x64 tiles

typedef __attribute__((ext_vector_type(8))) short bf16x8;
typedef __attribute__((ext_vector_type(4))) float f32x4;
typedef __attribute__((ext_vector_type(2))) float f32x2;

static constexpr float C_EXP = 2.8853900817779268f; // 2*log2(e)

// pack 8 fp32 -> 8 bf16 (RNE) as uint4
static __device__ __forceinline__ uint4 pack8(f32x4 a, f32x4 b) {
    union { uint4 u; __hip_bfloat162 h[4]; } r;
    r.h[0] = __float22bfloat162_rn(make_float2(a.x, a.y));
    r.h[1] = __float22bfloat162_rn(make_float2(a.z, a.w));
    r.h[2] = __float22bfloat162_rn(make_float2(b.x, b.y));
    r.h[3] = __float22bfloat162_rn(make_float2(b.z, b.w));
    return r.u;
}

static __device__ __forceinline__ f32x2 lo2(f32x4 v) { return __builtin_shufflevector(v, v, 0, 1); }
static __device__ __forceinline__ f32x2 hi2(f32x4 v) { return __builtin_shufflevector(v, v, 2, 3); }

// ---- forced VOP3P packed-fp32 ops (measured evidence: hipcc scalarizes
// f32x2 elementwise builtins — 9.5 slots/elem == exact scalarized count) ----
static __device__ __forceinline__ f32x2 pk_fma(f32x2 a, f32x2 b, f32x2 c) {
    f32x2 d; asm("v_pk_fma_f32 %0, %1, %2, %3" : "=v"(d) : "v"(a), "v"(b), "v"(c)); return d;
}
static __device__ __forceinline__ f32x2 pk_mul(f32x2 a, f32x2 b) {
    f32x2 d; asm("v_pk_mul_f32 %0, %1, %2" : "=v"(d) : "v"(a), "v"(b)); return d;
}
static __device__ __forceinline__ f32x2 pk_add(f32x2 a, f32x2 b) {
    f32x2 d; asm("v_pk_add_f32 %0, %1, %2" : "=v"(d) : "v"(a), "v"(b)); return d;
}
// a * {b.y, b.x}  (cross-half swap via op_sel, 1 instr, no movs)
static __device__ __forceinline__ f32x2 pk_mul_swap(f32x2 a, f32x2 b) {
    f32x2 d; asm("v_pk_mul_f32 %0, %1, %2 op_sel:[0,1] op_sel_hi:[1,0]" : "=v"(d) : "v"(a), "v"(b)); return d;
}
static __device__ __forceinline__ void pk_fma_acc(f32x2& acc, f32x2 a, f32x2 b) {
    asm("v_pk_fma_f32 %0, %1, %2, %0" : "+v"(acc) : "v"(a), "v"(b));
}

// ---------------------------------------------------------------------------
// Kernel 1: bf16 MFMA projection, 64m x 32n, grid 512 (r3 form, passed 2x).
//   n < 1024:  Ea[m][n] = exp2(C*(acc+b1[n]));  else Eb[m][n-1024] = exp2(C*acc)
// ---------------------------------------------------------------------------
__global__ __launch_bounds__(256, 4) void proj_mfma_kernel(
    const float* __restrict__ lm, const float* __restrict__ W1,
    const float* __restrict__ b1, float* __restrict__ Ea, float* __restrict__ Eb)
{
    __shared__ ushort As[64][136];  // 136 us = 68 dw = 4 mod 32 banks: <=2-way, free
    __shared__ ushort Bs[32][136];

    const int tid  = threadIdx.x;
    const int lane = tid & 63;
    const int w    = tid >> 6;
    const int b    = blockIdx.x;          // 0..511
    const int xcd  = b & 7;
    const int idx  = b >> 3;              // 0..63
    const int nbase = (xcd * 8 + (idx & 7)) * 32;   // 0..2047 (32-wide n-tile)
    const int mbase = (idx >> 3) * 64;              // 0..448
    const int wm   = w * 16;
    const int sel  = nbase >> 10;         // block-uniform: Wa(0)/Wb(1)
    const int nrow = nbase & 1023;

    const int frow = lane & 15;
    const int q8   = (lane >> 4) * 8;

    f32x4 acc[2] = {};

    for (int kb = 0; kb < HH; kb += 128) {
        __syncthreads();
        {   // stage A (64x128 -> 1024 chunks) + B (32x128 -> 512 chunks), 6/thread
            int p = tid;
#pragma unroll
            for (int it = 0; it < 4; ++it, p += 256) {      // A chunks
                const int row = p >> 4, c8 = (p & 15) * 8;
                const float* pa = &lm[(mbase + row) * HH + kb + c8];
                *(uint4*)&As[row][c8] = pack8(*(const f32x4*)pa, *(const f32x4*)(pa + 4));
            }
            int q = tid;
#pragma unroll
            for (int it = 0; it < 2; ++it, q += 256) {      // B chunks
                const int row = q >> 4, c8 = (q & 15) * 8;
                const float* pw = &W1[(nrow + row) * 2048 + sel * 1024 + kb + c8];
                *(uint4*)&Bs[row][c8] = pack8(*(const f32x4*)pw, *(const f32x4*)(pw + 4));
            }
        }
        __syncthreads();

#pragma unroll
        for (int s = 0; s < 4; ++s) {
            const bf16x8 a = *(const bf16x8*)&As[wm + frow][s * 32 + q8];
#pragma unroll
            for (int nf = 0; nf < 2; ++nf) {
                const bf16x8 bb = *(const bf16x8*)&Bs[nf * 16 + frow][s * 32 + q8];
                acc[nf] = __builtin_amdgcn_mfma_f32_16x16x32_bf16(a, bb, acc[nf], 0, 0, 0);
            }
        }
    }

    // D mapping: col=lane&15 (n), row=(lane>>4)*4+reg (m)
    const int col = lane & 15;
    const int rq  = (lane >> 4) * 4;
    const int m0  = mbase + wm + rq;
    const bool isA = sel == 0;            // block-uniform
#pragma unroll
    for (int nf = 0; nf < 2; ++nf) {
        const int nn = (nrow + nf * 16 + col);
        if (isA) {
            const float bb = b1[nn];
#pragma unroll
            for (int r = 0; r < 4; ++r)
                Ea[(m0 + r) * HH + nn] = __builtin_amdgcn_exp2f(C_EXP * (acc[nf][r] + bb));
        } else {
#pragma unroll
            for (int r = 0; r < 4; ++r)
                Eb[(m0 + r) * HH + nn] = __builtin_amdgcn_exp2f(C_EXP * acc[nf][r]);
        }
    }
}

// ---------------------------------------------------------------------------
// Kernel 2: triangular pairwise contraction — r3 shell VERBATIM (64x64 tile,
// 4x4/thread, h-adjacent pairs = natural .xy/.zw subregs of ds_read_b128:
// zero pk-operand marshaling), inner math forced to v_pk_* via inline asm.
// ~26 slots per (ii,jj,4h) = 3.25/ordered element vs 9.5 measured scalarized.
// ---------------------------------------------------------------------------
__global__ __launch_bounds__(256, 3) void pair_kernel(
    const float* __restrict__ Ea, const float* __restrict__ Eb,
    const float* __restrict__ W2, float* __restrict__ pbuf, int slice)
{
    __shared__ float tl[4][64][32];   // [0]=Ea[j] [1]=Eb[j] [2]=Ea[i] [3]=Eb[i]

    const int tid = threadIdx.x;
    const int tx  = tid & 15;
    const int ty  = tid >> 4;         // 0..15

    int tt = blockIdx.x, bi = 0, rem = TNT;          // triangular decode
    while (tt >= rem) { tt -= rem; --rem; ++bi; }
    const int bj    = bi + tt;
    const int ibase = bi * 64;
    const int jbase = bj * 64;
    const int k0    = blockIdx.y * slice;

    f32x2 acc0[4][4] = {};   // [ii][jj], h-packed partial sums, channel 0
    f32x2 acc1[4][4] = {};   // channel 1
    const f32x2 one2 = {1.f, 1.f};

    for (int kb = 0; kb < slice; kb += 32) {
        if (kb) __syncthreads();
        {   // stage 4 tiles x 64 rows x 32 floats = 2048 float4, 8/thread
            const int c4  = tid & 7;
            const int r0  = tid >> 3;                // 0..31
            const int hof = k0 + kb + c4 * 4;
#pragma unroll
            for (int it = 0; it < 8; ++it) {
                const int tile = it >> 1;            // compile-time per it
                const int row  = (it & 1) * 32 + r0;
                const int base = (tile < 2) ? jbase : ibase;
                const float* src = (tile == 0 || tile == 2) ? Ea : Eb;
                const int c4s = c4 ^ (row & 7);
                *(f32x4*)&tl[tile][row][c4s * 4] =
                    *(const f32x4*)&src[(size_t)(base + row) * HH + hof];
            }
        }
        __syncthreads();

#pragma unroll 2
        for (int h4 = 0; h4 < 8; ++h4) {
            const int sxj = (h4 ^ (tx & 7)) * 4;     // xor-swizzled float4 slot
            const int sxi = (h4 ^ (ty & 7)) * 4;

            // hoisted i-side (broadcast reads), split into pk-ready halves
            f32x2 ailo[4], aihi[4], bilo[4], bihi[4];
#pragma unroll
            for (int ii = 0; ii < 4; ++ii) {
                const f32x4 Ai = *(const f32x4*)&tl[2][ty + 16 * ii][sxi];
                const f32x4 Bi = *(const f32x4*)&tl[3][ty + 16 * ii][sxi];
                ailo[ii] = lo2(Ai); aihi[ii] = hi2(Ai);
                bilo[ii] = lo2(Bi); bihi[ii] = hi2(Bi);
            }
            const f32x4 w0q = *(const f32x4*)&W2[k0 + kb + h4 * 4];      // uniform
            const f32x4 w1q = *(const f32x4*)&W2[HH + k0 + kb + h4 * 4];
            const f32x2 w0lo = lo2(w0q), w0hi = hi2(w0q);
            const f32x2 w1lo = lo2(w1q), w1hi = hi2(w1q);

#pragma unroll
            for (int jj = 0; jj < 4; ++jj) {
                const f32x4 Aj = *(const f32x4*)&tl[0][tx + 16 * jj][sxj];
                const f32x4 Bj = *(const f32x4*)&tl[1][tx + 16 * jj][sxj];
                const f32x2 ajlo = lo2(Aj), ajhi = hi2(Aj);
                const f32x2 bjlo = lo2(Bj), bjhi = hi2(Bj);
#pragma unroll
                for (int ii = 0; ii < 4; ++ii) {
                    // d = 1 + Eb_i*Ea_j ; e = 1 + Ea_i*Eb_j   (h-packed pairs)
                    const f32x2 d01 = pk_fma(bilo[ii], ajlo, one2);
                    const f32x2 d23 = pk_fma(bihi[ii], ajhi, one2);
                    const f32x2 e01 = pk_fma(ailo[ii], bjlo, one2);
                    const f32x2 e23 = pk_fma(aihi[ii], bjhi, one2);
                    // 1/d + 1/e = (d+e)/(d*e); batch-rcp the 4 products (>=1)
                    const f32x2 n01 = pk_add(d01, e01);
                    const f32x2 n23 = pk_add(d23, e23);
                    const f32x2 m01 = pk_mul(d01, e01);
                    const f32x2 m23 = pk_mul(d23, e23);
                    const float p01 = m01.x * m01.y;
                    const float p23 = m23.x * m23.y;
                    const float R   = __builtin_amdgcn_rcpf(p01 * p23);
                    const float r01 = R * p23;       // = 1/p01
                    const float r23 = R * p01;       // = 1/p23
                    const f32x2 t01 = pk_mul_swap(n01, m01);   // n01*{m01.y,m01.x}
                    const f32x2 t23 = pk_mul_swap(n23, m23);
                    const f32x2 u01 = pk_mul(t01, (f32x2){r01, r01});
                    const f32x2 u23 = pk_mul(t23, (f32x2){r23, r23});
                    pk_fma_acc(acc0[ii][jj], u01, w0lo);
                    pk_fma_acc(acc0[ii][jj], u23, w0hi);
                    pk_fma_acc(acc1[ii][jj], u01, w1lo);
                    pk_fma_acc(acc1[ii][jj], u23, w1hi);
                }
            }
        }
    }

    float* pb = pbuf + ((size_t)blockIdx.y * NTILE + blockIdx.x) * 8192;
#pragma unroll
    for (int ii = 0; ii < 4; ++ii)
#pragma unroll
        for (int jj = 0; jj < 4; ++jj) {
            const int li = ty + 16 * ii, lj = tx + 16 * jj;
            const f32x2 v = { acc0[ii][jj].x + acc0[ii][jj].y,
                              acc1[ii][jj].x + acc1[ii][jj].y };
            *(f32x2*)&pb[(li * 64 + lj) * 2] = v;
        }
}

// ---------------------------------------------------------------------------
// Kernel 3: combine: out = wsum[c]+b2[c] - sum_z pbuf; scatter (i,j),(j,i).
// 1152 blocks over 36 tiles x 64x64x2; 4-way ILP on z. (r3 form, passed.)
// ---------------------------------------------------------------------------
__global__ __launch_bounds__(256) void combine_kernel(
    const float* __restrict__ pbuf, const float* __restrict__ W2,
    const float* __restrict__ b2, float* __restrict__ out, int nz)
{
    __shared__ float s_ws[2];

    const int tid = threadIdx.x;
    if (tid < 128) {
        const int c = tid >> 6, l = tid & 63;
        float s = 0.f;
#pragma unroll
        for (int q = 0; q < 4; ++q) {
            const f32x4 v = *(const f32x4*)&W2[c * HH + (l + q * 64) * 4];
            s += v.x + v.y + v.z + v.w;
        }
#pragma unroll
        for (int off = 32; off; off >>= 1) s += __shfl_down(s, off, 64);
        if (l == 0) s_ws[c] = s + b2[c];
    }
    __syncthreads();

    const int idx   = blockIdx.x * 256 + tid;   // 0 .. 36*8192-1
    const int t     = idx >> 13;                // block-uniform (8192/256=32)
    const int local = idx & 8191;
    int tt = t, bi = 0, rem = TNT;
    while (tt >= rem) { tt -= rem; --rem; ++bi; }
    const int bj = bi + tt;

    float s0 = 0.f, s1 = 0.f, s2 = 0.f, s3 = 0.f;
    for (int z = 0; z < nz; z += 4) {   // nz in {8,16,32}
        s0 += pbuf[((size_t)z * NTILE + t) * 8192 + local];
        s1 += pbuf[((size_t)(z + 1) * NTILE + t) * 8192 + local];
        s2 += pbuf[((size_t)(z + 2) * NTILE + t) * 8192 + local];
        s3 += pbuf[((size_t)(z + 3) * NTILE + t) * 8192 + local];
    }
    const float s = (s0 + s1) + (s2 + s3);

    const int li = local >> 7;          // 0..63
    const int lj = (local >> 1) & 63;
    const int c  = local & 1;
    const float v = s_ws[c] - s;

    const int i = bi * 64 + li;
    const int j = bj * 64 + lj;
    out[(i * LL + j) * 2 + c] = v;
    out[(j * LL + i) * 2 + c] = v;   // diagonal tiles: same-value rewrite, benign
}

extern "C" void kernel_launch(void* const* d_in, const int* in_sizes, int n_in,
                              void* d_out, int out_size, void* d_ws, size_t ws_size,
                              hipStream_t stream)
{
    const float* lm = (const float*)d_in[0];
    const float* W1 = (const float*)d_in[1];
    const float* b1 = (const float*)d_in[2];
    const float* W2 = (const float*)d_in[3];
    const float* b2 = (const float*)d_in[4];
    float* out = (float*)d_out;

    char* ws = (char*)d_ws;
    float* Ea   = (float*)ws;                            // 2 MB
    float* Eb   = (float*)(ws + (2u << 20));             // 2 MB
    float* pbuf = (float*)(ws + (4u << 20) + 64);        // nz * 1.18 MB

    const size_t ubase = (4u << 20) + 64;
    const size_t per_z = (size_t)NTILE * 8192 * 4;       // 1.18 MB per z-slice
    int nz = 8;                                          // 288 blocks (safe floor)
    if      (ws_size >= ubase + 32 * per_z) nz = 32;     // 1152 blocks, 4.5/CU
    else if (ws_size >= ubase + 16 * per_z) nz = 16;     // 576 blocks
    const int slice = HH / nz;

    proj_mfma_kernel<<<512, 256, 0, stream>>>(lm, W1, b1, Ea, Eb);
    pair_kernel<<<dim3(NTILE, nz), 256, 0, stream>>>(Ea, Eb, W2, pbuf, slice);
    combine_kernel<<<(NTILE * 8192) / 256, 256, 0, stream>>>(pbuf, W2, b2, out, nz);
}

// Round 9
// 128.072 us; speedup vs baseline: 1.2998x; 1.0202x over previous
//
#include <hip/hip_runtime.h>
#include <hip/hip_bf16.h>

#define HH 1024
#define LL 512
#define NT 16              // 512/32 row-tiles
#define NTRI 136           // NT*(NT+1)/2 triangular tiles
#define NZ 8               // z-slices: slice=128 -> 4 K-phases of 32/block

typedef __attribute__((ext_vector_type(8))) short bf16x8;
typedef __attribute__((ext_vector_type(4))) float f32x4;
typedef __attribute__((ext_vector_type(2))) float f32x2;

static constexpr float C_EXP = 2.8853900817779268f; // 2*log2(e)

// pack 8 fp32 -> 8 bf16 (RNE) as uint4
static __device__ __forceinline__ uint4 pack8(f32x4 a, f32x4 b) {
    union { uint4 u; __hip_bfloat162 h[4]; } r;
    r.h[0] = __float22bfloat162_rn(make_float2(a.x, a.y));
    r.h[1] = __float22bfloat162_rn(make_float2(a.z, a.w));
    r.h[2] = __float22bfloat162_rn(make_float2(b.x, b.y));
    r.h[3] = __float22bfloat162_rn(make_float2(b.z, b.w));
    return r.u;
}

// ---------------------------------------------------------------------------
// Kernel 1: bf16 MFMA projection, 64m x 32n, grid 512 (r8 form, passed).
// ---------------------------------------------------------------------------
__global__ __launch_bounds__(256, 4) void proj_mfma_kernel(
    const float* __restrict__ lm, const float* __restrict__ W1,
    const float* __restrict__ b1, float* __restrict__ Ea, float* __restrict__ Eb)
{
    __shared__ ushort As[64][136];  // 136 us = 68 dw = 4 mod 32 banks: <=2-way, free
    __shared__ ushort Bs[32][136];

    const int tid  = threadIdx.x;
    const int lane = tid & 63;
    const int w    = tid >> 6;
    const int b    = blockIdx.x;          // 0..511
    const int xcd  = b & 7;
    const int idx  = b >> 3;              // 0..63
    const int nbase = (xcd * 8 + (idx & 7)) * 32;   // 0..2047 (32-wide n-tile)
    const int mbase = (idx >> 3) * 64;              // 0..448
    const int wm   = w * 16;
    const int sel  = nbase >> 10;         // block-uniform: Wa(0)/Wb(1)
    const int nrow = nbase & 1023;

    const int frow = lane & 15;
    const int q8   = (lane >> 4) * 8;

    f32x4 acc[2] = {};

    for (int kb = 0; kb < HH; kb += 128) {
        __syncthreads();
        {   // stage A (64x128) + B (32x128), 6 chunks/thread
            int p = tid;
#pragma unroll
            for (int it = 0; it < 4; ++it, p += 256) {      // A chunks
                const int row = p >> 4, c8 = (p & 15) * 8;
                const float* pa = &lm[(mbase + row) * HH + kb + c8];
                *(uint4*)&As[row][c8] = pack8(*(const f32x4*)pa, *(const f32x4*)(pa + 4));
            }
            int q = tid;
#pragma unroll
            for (int it = 0; it < 2; ++it, q += 256) {      // B chunks
                const int row = q >> 4, c8 = (q & 15) * 8;
                const float* pw = &W1[(nrow + row) * 2048 + sel * 1024 + kb + c8];
                *(uint4*)&Bs[row][c8] = pack8(*(const f32x4*)pw, *(const f32x4*)(pw + 4));
            }
        }
        __syncthreads();

#pragma unroll
        for (int s = 0; s < 4; ++s) {
            const bf16x8 a = *(const bf16x8*)&As[wm + frow][s * 32 + q8];
#pragma unroll
            for (int nf = 0; nf < 2; ++nf) {
                const bf16x8 bb = *(const bf16x8*)&Bs[nf * 16 + frow][s * 32 + q8];
                acc[nf] = __builtin_amdgcn_mfma_f32_16x16x32_bf16(a, bb, acc[nf], 0, 0, 0);
            }
        }
    }

    const int col = lane & 15;
    const int rq  = (lane >> 4) * 4;
    const int m0  = mbase + wm + rq;
    const bool isA = sel == 0;
#pragma unroll
    for (int nf = 0; nf < 2; ++nf) {
        const int nn = (nrow + nf * 16 + col);
        if (isA) {
            const float bb = b1[nn];
#pragma unroll
            for (int r = 0; r < 4; ++r)
                Ea[(m0 + r) * HH + nn] = __builtin_amdgcn_exp2f(C_EXP * (acc[nf][r] + bb));
        } else {
#pragma unroll
            for (int r = 0; r < 4; ++r)
                Eb[(m0 + r) * HH + nn] = __builtin_amdgcn_exp2f(C_EXP * acc[nf][r]);
        }
    }
}

// ---------------------------------------------------------------------------
// Kernel 2: pairwise contraction — r0 math VERBATIM; staging restructured to
// 4 K-phases of 32 with double-buffered LDS halves (2 x 16 KB) filled by
// global_load_lds (no staging registers -> no r7 spill). Source address is
// pre-swizzled for the j-tiles (XOR involution, m173/m201 pattern); i-tiles
// linear (broadcast reads are conflict-immune). __syncthreads at phase end
// drains exactly the prefetch we need next (in-phase overlap, no raw asm).
// ---------------------------------------------------------------------------
__global__ __launch_bounds__(256, 4) void pair_kernel(
    const float* __restrict__ Ea, const float* __restrict__ Eb,
    const float* __restrict__ W2, float* __restrict__ pbuf, int slice)
{
    // [buf][tile][row][col]: tile 0=Ea[j](xor) 1=Ea[i] 2=Eb[i] 3=Eb[j](xor)
    __shared__ float tl[2][4][32][32];   // 32768 B

    const int tid = threadIdx.x;
    const int tx  = tid & 15;
    const int ty  = tid >> 4;         // 0..15

    int tt = blockIdx.x, bi = 0, rem = NT;          // triangular decode
    while (tt >= rem) { tt -= rem; --rem; ++bi; }
    const int bj    = bi + tt;
    const int ibase = bi * 32;
    const int jbase = bj * 32;
    const int k0    = blockIdx.y * slice;           // slice = 128

    f32x2 aC0[2] = {}, aC1[2] = {};   // [ii], packed over jj
    const f32x2 one2 = {1.f, 1.f};

    // wave w stages tile w: 4 x global_load_lds(16B) covering 8 rows each.
    const int wv = tid >> 6, ln = tid & 63;
    const int rr = ln >> 3, ss = ln & 7;
    const float* mat   = (wv <= 1) ? Ea : Eb;
    const int    rbase = (wv == 0 || wv == 3) ? jbase : ibase;
    const bool   swz   = (wv == 0 || wv == 3);

#define STAGE(b, kk)                                                           \
    {                                                                          \
        _Pragma("unroll")                                                      \
        for (int k = 0; k < 4; ++k) {                                          \
            const int row = k * 8 + rr;                                        \
            const int sc  = swz ? (ss ^ (row & 7)) : ss;                       \
            const float* g = &mat[(size_t)(rbase + row) * HH + (kk) + sc * 4]; \
            __builtin_amdgcn_global_load_lds(                                  \
                (const __attribute__((address_space(1))) unsigned int*)g,      \
                (__attribute__((address_space(3))) unsigned int*)&tl[b][wv][k * 8][0], \
                16, 0, 0);                                                     \
        }                                                                      \
    }

#define DO_H(AJ0v, AJ1v, BI0v, BI1v, AI0v, AI1v, BJ0v, BJ1v, W0s, W1s)        \
    {                                                                          \
        const f32x2 Aj = {AJ0v, AJ1v};                                         \
        const f32x2 Bj = {BJ0v, BJ1v};                                         \
        const f32x2 d0 = __builtin_elementwise_fma((f32x2){BI0v, BI0v}, Aj, one2); \
        const f32x2 d1 = __builtin_elementwise_fma((f32x2){BI1v, BI1v}, Aj, one2); \
        const f32x2 e0 = __builtin_elementwise_fma((f32x2){AI0v, AI0v}, Bj, one2); \
        const f32x2 e1 = __builtin_elementwise_fma((f32x2){AI1v, AI1v}, Bj, one2); \
        const float dp0 = d0.x * d0.y, dp1 = d1.x * d1.y;                      \
        const float ep0 = e0.x * e0.y, ep1 = e1.x * e1.y;                      \
        const float DR = __builtin_amdgcn_rcpf(dp0 * dp1);                     \
        const float ER = __builtin_amdgcn_rcpf(ep0 * ep1);                     \
        const f32x2 dq = (f32x2){DR, DR} * (f32x2){dp1, dp0};                  \
        const f32x2 eq = (f32x2){ER, ER} * (f32x2){ep1, ep0};                  \
        const f32x2 u0 = (f32x2){dq.x, dq.x} * __builtin_shufflevector(d0, d0, 1, 0) \
                       + (f32x2){eq.x, eq.x} * __builtin_shufflevector(e0, e0, 1, 0); \
        const f32x2 u1 = (f32x2){dq.y, dq.y} * __builtin_shufflevector(d1, d1, 1, 0) \
                       + (f32x2){eq.y, eq.y} * __builtin_shufflevector(e1, e1, 1, 0); \
        aC0[0] = __builtin_elementwise_fma(u0, (f32x2){(W0s), (W0s)}, aC0[0]); \
        aC1[0] = __builtin_elementwise_fma(u0, (f32x2){(W1s), (W1s)}, aC1[0]); \
        aC0[1] = __builtin_elementwise_fma(u1, (f32x2){(W0s), (W0s)}, aC0[1]); \
        aC1[1] = __builtin_elementwise_fma(u1, (f32x2){(W1s), (W1s)}, aC1[1]); \
    }

#define COMPUTE(b, kk)                                                         \
    _Pragma("unroll 4")                                                        \
    for (int h4 = 0; h4 < 8; ++h4) {                                           \
        const int sx = (h4 ^ (tx & 7)) * 4;      /* xor-swizzled slot */       \
        const f32x4 Aj0 = *(const f32x4*)&tl[b][0][tx][sx];                    \
        const f32x4 Aj1 = *(const f32x4*)&tl[b][0][tx + 16][sx];               \
        const f32x4 Bj0 = *(const f32x4*)&tl[b][3][tx][sx];                    \
        const f32x4 Bj1 = *(const f32x4*)&tl[b][3][tx + 16][sx];               \
        const f32x4 Ai0 = *(const f32x4*)&tl[b][1][ty][h4 * 4];                \
        const f32x4 Ai1 = *(const f32x4*)&tl[b][1][ty + 16][h4 * 4];           \
        const f32x4 Bi0 = *(const f32x4*)&tl[b][2][ty][h4 * 4];                \
        const f32x4 Bi1 = *(const f32x4*)&tl[b][2][ty + 16][h4 * 4];           \
        const f32x4 w0q = *(const f32x4*)&W2[k0 + (kk) + h4 * 4];              \
        const f32x4 w1q = *(const f32x4*)&W2[HH + k0 + (kk) + h4 * 4];         \
        DO_H(Aj0.x, Aj1.x, Bi0.x, Bi1.x, Ai0.x, Ai1.x, Bj0.x, Bj1.x, w0q.x, w1q.x) \
        DO_H(Aj0.y, Aj1.y, Bi0.y, Bi1.y, Ai0.y, Ai1.y, Bj0.y, Bj1.y, w0q.y, w1q.y) \
        DO_H(Aj0.z, Aj1.z, Bi0.z, Bi1.z, Ai0.z, Ai1.z, Bj0.z, Bj1.z, w0q.z, w1q.z) \
        DO_H(Aj0.w, Aj1.w, Bi0.w, Bi1.w, Ai0.w, Ai1.w, Bj0.w, Bj1.w, w0q.w, w1q.w) \
    }

    // --- 4-phase pipelined K loop: stage(next) overlaps compute(cur) ---
    STAGE(0, k0)
    __syncthreads();                       // drain prologue stage
#pragma unroll
    for (int ph = 0; ph < 4; ++ph) {
        if (ph < 3) STAGE((ph + 1) & 1, k0 + (ph + 1) * 32)   // async prefetch
        COMPUTE(ph & 1, ph * 32)
        if (ph < 3) __syncthreads();       // drains prefetch (it had full compute to fly)
    }

#undef COMPUTE
#undef DO_H
#undef STAGE

    // u0/u1 are jj-packed: value(ii,jj,c) = (c ? aC1 : aC0)[ii][jj]
    float* pb = pbuf + ((size_t)blockIdx.y * NTRI + blockIdx.x) * 2048;
#pragma unroll
    for (int ii = 0; ii < 2; ++ii)
#pragma unroll
        for (int jj = 0; jj < 2; ++jj) {
            const int li = ty + ii * 16, lj = tx + jj * 16;
            const f32x2 v = { jj ? aC0[ii].y : aC0[ii].x,
                              jj ? aC1[ii].y : aC1[ii].x };
            *(f32x2*)&pb[(li * 32 + lj) * 2] = v;
        }
}

// ---------------------------------------------------------------------------
// Kernel 3: combine (r7 form, passed): out = wsum[c]+b2[c] - sum_z pbuf.
// nz=8 -> 8.9 MB pbuf reads (half of nz16). 1088 blocks, 4-way ILP on z.
// ---------------------------------------------------------------------------
__global__ __launch_bounds__(256) void combine_kernel(
    const float* __restrict__ pbuf, const float* __restrict__ W2,
    const float* __restrict__ b2, float* __restrict__ out, int nz)
{
    __shared__ float s_ws[2];

    const int tid = threadIdx.x;
    if (tid < 128) {
        const int c = tid >> 6, l = tid & 63;
        float s = 0.f;
#pragma unroll
        for (int q = 0; q < 4; ++q) {
            const f32x4 v = *(const f32x4*)&W2[c * HH + (l + q * 64) * 4];
            s += v.x + v.y + v.z + v.w;
        }
#pragma unroll
        for (int off = 32; off; off >>= 1) s += __shfl_down(s, off, 64);
        if (l == 0) s_ws[c] = s + b2[c];
    }
    __syncthreads();

    const int idx   = blockIdx.x * 256 + tid;   // 0 .. 136*2048-1
    const int t     = idx >> 11;                // block-uniform
    const int local = idx & 2047;
    int tt = t, bi = 0, rem = NT;
    while (tt >= rem) { tt -= rem; --rem; ++bi; }
    const int bj = bi + tt;

    float s0 = 0.f, s1 = 0.f, s2 = 0.f, s3 = 0.f;
    for (int z = 0; z < nz; z += 4) {   // nz = 8 -> 2 iterations
        s0 += pbuf[((size_t)z * NTRI + t) * 2048 + local];
        s1 += pbuf[((size_t)(z + 1) * NTRI + t) * 2048 + local];
        s2 += pbuf[((size_t)(z + 2) * NTRI + t) * 2048 + local];
        s3 += pbuf[((size_t)(z + 3) * NTRI + t) * 2048 + local];
    }
    const float s = (s0 + s1) + (s2 + s3);

    const int li = local >> 6;
    const int lj = (local >> 1) & 31;
    const int c  = local & 1;
    const float v = s_ws[c] - s;

    const int i = bi * 32 + li;
    const int j = bj * 32 + lj;
    out[(i * LL + j) * 2 + c] = v;
    out[(j * LL + i) * 2 + c] = v;   // diagonal tiles: same-value rewrite, benign
}

extern "C" void kernel_launch(void* const* d_in, const int* in_sizes, int n_in,
                              void* d_out, int out_size, void* d_ws, size_t ws_size,
                              hipStream_t stream)
{
    const float* lm = (const float*)d_in[0];
    const float* W1 = (const float*)d_in[1];
    const float* b1 = (const float*)d_in[2];
    const float* W2 = (const float*)d_in[3];
    const float* b2 = (const float*)d_in[4];
    float* out = (float*)d_out;

    char* ws = (char*)d_ws;
    float* Ea   = (float*)ws;                            // 2 MB
    float* Eb   = (float*)(ws + (2u << 20));             // 2 MB
    float* pbuf = (float*)(ws + (4u << 20) + 64);        // 8 * 1.11 MB = 8.9 MB

    const int nz = NZ;                 // 8; session ws = 256 MB (proven by fills)
    const int slice = HH / nz;         // 128 -> 4 K-phases of 32 per pair block

    proj_mfma_kernel<<<512, 256, 0, stream>>>(lm, W1, b1, Ea, Eb);
    pair_kernel<<<dim3(NTRI, nz), 256, 0, stream>>>(Ea, Eb, W2, pbuf, slice);
    combine_kernel<<<(NTRI * 2048) / 256, 256, 0, stream>>>(pbuf, W2, b2, out, nz);
}